// Round 6
// baseline (35.159 us; speedup 1.0000x reference)
//
#include <hip/hip_runtime.h>
#include <stdint.h>

#define BATCH 32
#define NA    8400
#define NL    80
#define NH    256
#define NK    300
#define NBIN  8192   // 13-bit key = mapped-u32 >> 19

// output float offsets (concatenated return order)
#define OUT0 0                       // init_reference_points (32,300,4)
#define OUT1 38400                   // target                (32,300,256)
#define OUT2 2496000                 // enc_topk_logits       (32,300,80)
#define OUT3 3264000                 // enc_topk_bboxes       (32,300,4)

__device__ __forceinline__ unsigned mapf(float f) {
    unsigned u = __float_as_uint(f);
    return (u & 0x80000000u) ? ~u : (u | 0x80000000u);
}

// Kernel 1: per-(b,a) max over L=80 -> monotone-mapped u32.
// LDS-staged: 64 rows (20KB) per 256-thread block. Global loads are
// fully contiguous (each wave = 1KB, each 128B line consumed by exactly
// one instruction) — fixes the 64B-granule/320B-stride half-line
// over-fetch of the previous version. 20KB LDS -> 8 blocks/CU.
__global__ __launch_bounds__(256) void cls_max_kernel(const float* __restrict__ cls,
                                                      unsigned* __restrict__ out_u) {
    __shared__ float4 smem[1280];                    // 64 rows * 20 float4
    int tid = threadIdx.x;
    size_t base = (size_t)blockIdx.x * 1280;         // float4 index of tile
    const float4* g = (const float4*)cls;

    float4 v0 = g[base + tid];
    float4 v1 = g[base + tid + 256];
    float4 v2 = g[base + tid + 512];
    float4 v3 = g[base + tid + 768];
    float4 v4 = g[base + tid + 1024];
    smem[tid]        = v0;
    smem[tid + 256]  = v1;
    smem[tid + 512]  = v2;
    smem[tid + 768]  = v3;
    smem[tid + 1024] = v4;
    __syncthreads();

    int r   = tid >> 2;                              // local row 0..63
    int sub = tid & 3;
    const float4* rp = &smem[r * 20 + sub * 5];
    float m = -3.4e38f;
#pragma unroll
    for (int e = 0; e < 5; ++e) {
        float4 w = rp[e];
        m = fmaxf(m, fmaxf(fmaxf(w.x, w.y), fmaxf(w.z, w.w)));
    }
    m = fmaxf(m, __shfl_xor(m, 1));
    m = fmaxf(m, __shfl_xor(m, 2));
    if (sub == 0) out_u[blockIdx.x * 64 + r] = mapf(m);
}

// Kernel 2 (fused select + gather): 8 blocks per batch, 1024 threads.
// Each block redundantly computes the exact top-300 of its batch
// (registers + LDS 8192-bin histogram + shuffle suffix-scan +
// barrier-free rank-by-comparison), then gathers queries q≡sub (mod 8).
__global__ __launch_bounds__(1024) void select_gather_kernel(
        const unsigned* __restrict__ u_in,
        const float*    __restrict__ cls,
        const float*    __restrict__ coord,
        const float*    __restrict__ mem,
        float*          __restrict__ out) {
    __shared__ unsigned hist[NBIN];                 // 32 KB
    __shared__ unsigned long long keys[1024];       // 8 KB
    __shared__ int ord[NK];
    __shared__ unsigned wsum[16], wsuf[16];
    __shared__ unsigned s_thr, s_count;

    int tid  = threadIdx.x;
    int lane = tid & 63;
    int wid  = tid >> 6;
    int b    = blockIdx.x >> 3;
    int sub  = blockIdx.x & 7;
    const unsigned* ub = u_in + b * NA;

    // issue global loads FIRST (HBM latency hides under hist zeroing)
    unsigned v[9];
#pragma unroll
    for (int k = 0; k < 9; ++k) {
        int i = tid + k * 1024;
        v[k] = (i < NA) ? ub[i] : 0u;               // 0 -> bin 0, never selected
    }

    for (int i = tid; i < NBIN; i += 1024) hist[i] = 0;
    if (tid == 0) s_count = 0;
    __syncthreads();

#pragma unroll
    for (int k = 0; k < 9; ++k) {
        int i = tid + k * 1024;
        if (i < NA) atomicAdd(&hist[v[k] >> 19], 1u);
    }
    __syncthreads();

    // hierarchical suffix scan over 8192 bins; thread owns [tid*8, tid*8+8)
    unsigned base = tid * 8;
    unsigned h[8];
#pragma unroll
    for (int j = 0; j < 8; ++j) h[j] = hist[base + j];
    unsigned L = 0;
#pragma unroll
    for (int j = 0; j < 8; ++j) L += h[j];
    unsigned s = L;                                  // inclusive suffix within wave
#pragma unroll
    for (int off = 1; off < 64; off <<= 1) {
        unsigned t = __shfl_down(s, off);
        if (lane + off < 64) s += t;
    }
    if (lane == 0) wsum[wid] = s;
    __syncthreads();
    if (tid == 0) {
        unsigned acc = 0;
        for (int w = 15; w >= 0; --w) { acc += wsum[w]; wsuf[w] = acc; }
    }
    __syncthreads();
    unsigned above = (wid < 15 ? wsuf[wid + 1] : 0u) + (s - L);
    unsigned acc = above;
#pragma unroll
    for (int j = 7; j >= 0; --j) {
        unsigned S = acc + h[j];
        if (S >= (unsigned)NK && acc < (unsigned)NK) s_thr = base + (unsigned)j;
        acc = S;
    }
    __syncthreads();

    // collect candidates from registers (no global re-read)
    unsigned T = s_thr;
#pragma unroll
    for (int k = 0; k < 9; ++k) {
        int i = tid + k * 1024;
        if (i < NA && (v[k] >> 19) >= T) {
            unsigned pos = atomicAdd(&s_count, 1u);
            if (pos < 1024) keys[pos] = ((unsigned long long)(~v[k]) << 32) | (unsigned)i;
        }
    }
    __syncthreads();

    // rank-by-comparison: key asc == (u desc, idx asc); deterministic
    unsigned count = s_count < 1024u ? s_count : 1024u;
    if (tid < (int)count) {
        unsigned long long mykey = keys[tid];
        int rank = 0;
        for (unsigned j = 0; j < count; ++j) rank += (keys[j] < mykey);
        if (rank < NK) ord[rank] = (int)(mykey & 0xFFFFFFFFull);
    }
    __syncthreads();

    // gather: this block handles queries q ≡ sub (mod 8); one wave per query
    for (int q = sub + 8 * wid; q < NK; q += 8 * 16) {
        int idx = ord[q];
        size_t srow = (size_t)b * NA + (size_t)idx;
        size_t drow = (size_t)b * NK + (size_t)q;

        const float4* msrc = (const float4*)(mem + srow * NH);
        float4*       mdst = (float4*)(out + OUT1 + drow * NH);
        mdst[lane] = msrc[lane];

        if (lane < 20) {
            const float4* lsrc = (const float4*)(cls + srow * NL);
            float4*       ldst = (float4*)(out + OUT2 + drow * NL);
            ldst[lane] = lsrc[lane];
        }
        if (lane == 0) {
            float4 c = ((const float4*)(coord + srow * 4))[0];
            ((float4*)(out + OUT0 + drow * 4))[0] = c;
            float4 sg;
            sg.x = 1.0f / (1.0f + __expf(-c.x));
            sg.y = 1.0f / (1.0f + __expf(-c.y));
            sg.z = 1.0f / (1.0f + __expf(-c.z));
            sg.w = 1.0f / (1.0f + __expf(-c.w));
            ((float4*)(out + OUT3 + drow * 4))[0] = sg;
        }
    }
}

extern "C" void kernel_launch(void* const* d_in, const int* in_sizes, int n_in,
                              void* d_out, int out_size, void* d_ws, size_t ws_size,
                              hipStream_t stream) {
    const float* cls   = (const float*)d_in[0]; // (32,8400,80)
    const float* coord = (const float*)d_in[1]; // (32,8400,4)
    const float* mem   = (const float*)d_in[2]; // (32,8400,256)
    // d_in[3] (sources_last_element) unused by the reference

    unsigned* ws_u = (unsigned*)d_ws;           // 32*8400 u32
    float*    out  = (float*)d_out;

    cls_max_kernel<<<(BATCH * NA) / 64, 256, 0, stream>>>(cls, ws_u);
    select_gather_kernel<<<BATCH * 8, 1024, 0, stream>>>(ws_u, cls, coord, mem, out);
}